// Round 2
// baseline (208.493 us; speedup 1.0000x reference)
//
#include <hip/hip_runtime.h>

// Spatial transformer: affine grid-sample, reflect padding, bilinear.
// x: (B=32, C=3, H=512, W=512) fp32; p: (B,4) fp32 = [tx, ty, theta, scale].
//
// R5 == R4 with the compile fix: __builtin_nontemporal_store needs a native
// clang vector type, not HIP's float4 class. Use ext_vector_type(4).
//
// R4 rationale: VALU-issue bound at 62% VALUBusy / 28% HBM. Changes vs R3:
//  - 32x32 tile/block (4x fewer blocks -> 4x less redundant per-thread setup),
//    4 px/thread with float4 stores, ix/iy stepped incrementally (+a / +d per col).
//  - __cosf/__sinf (v_cos/v_sin) instead of branchy libm range reduction.
//  - reflect as exact triangle wave: 512 - |c mod 1024 - 512| (bit-identical to
//    ref for pow2 sizes: /1024, floor, fma all exact), no fmodf, no cndmask.
//  - staging box 56x56 (stride 60) with zero-filled pad column + one zero guard
//    row: x0+1 / y0+1 taps are ALWAYS in-box (weight is exactly 0 when they hit
//    a pad), so x1/y1 clamps vanish and each channel gather is 2x ds_read2_b32.
//  - LDS 40,560 B -> exactly 4 blocks/CU (16 waves/CU).

#define B_ 32
#define C_ 3
#define H_ 512
#define W_ 512
#define TILE 32
#define BOX 56
#define LSTRIDE 60                    // 56 data + 4 pad words; rows 16B-aligned
#define CH_WORDS (BOX * LSTRIDE)      // 3360 words per channel

typedef float f32x4 __attribute__((ext_vector_type(4)));

// reflect onto [0, 511] with the reference's half-pixel convention.
// Exact for size=512: /1024 and *1024 are exact (pow2), floor exact, the mod
// subtraction is exact, so this is bit-identical to floor/fmod/parity form.
__device__ __forceinline__ float reflect512(float coord) {
    const float c = fabsf(coord + 0.5f);
    const float m = c - floorf(c * (1.0f / 1024.0f)) * 1024.0f;   // c mod 1024
    const float t = 512.0f - fabsf(m - 512.0f);
    return fminf(fmaxf(t - 0.5f, 0.0f), 511.0f);
}

__global__ __launch_bounds__(256, 4)
void st_kernel(const float* __restrict__ x, const float* __restrict__ p,
               float* __restrict__ out) {
    __shared__ float smem[C_ * CH_WORDS + LSTRIDE];   // 40,560 B

    const int tid = threadIdx.x;
    const int b   = blockIdx.z;                 // wave-uniform -> scalar loads

    const float tx = p[b * 4 + 0];
    const float ty = p[b * 4 + 1];
    const float th = p[b * 4 + 2];
    const float ts = p[b * 4 + 3];
    const float cth = __cosf(th), sth = __sinf(th);   // th in [0,1): well-conditioned
    const float a  =  ts * cth;                 // ix step per output col
    const float bb = -ts * sth;                 // ix step per output row
    const float d  =  ts * sth;                 // iy step per output col (e == a)

    // ---- block-uniform staging box (center of the 32x32 tile) ----
    const float xs_c = ((float)(blockIdx.x * TILE) + 16.0f) * (2.0f / W_) - 1.0f;
    const float ys_c = ((float)(blockIdx.y * TILE) + 16.0f) * (2.0f / H_) - 1.0f;
    const float gxc = a * xs_c + bb * ys_c + tx;
    const float gyc = d * xs_c + a  * ys_c + ty;
    const float rcx = reflect512(((gxc + 1.0f) * W_ - 1.0f) * 0.5f);
    const float rcy = reflect512(((gyc + 1.0f) * H_ - 1.0f) * 0.5f);
    // footprint half-extent: 15.5*(|a|+|bb|); +3 covers floor + 4-align slack.
    // worst case 16*sqrt(2)+3 = 25.6 -> 2*ext+2+align(3) = 54.3 <= BOX=56.
    const float ext = 16.0f * (fabsf(a) + fabsf(bb)) + 3.0f;
    int bx0 = (int)floorf(rcx - ext);
    bx0 = (min(max(bx0, 0), W_ - BOX)) & ~3;    // 16B-aligned float4 staging
    int by0 = (int)floorf(rcy - ext);
    by0 = min(max(by0, 0), H_ - BOX);

    const size_t plane = (size_t)H_ * W_;
    const float* img = x + (size_t)b * C_ * plane;

    // ---- stage 56x56 x 3ch into LDS, coalesced float4; zero the pad column ----
    // 15 float4 per row (last one = pad words 56..59, written as zeros so any
    // weight-0 tap that lands there is finite). 16 threads/row-slot, c4==15 idle.
    {
        const int c4 = tid & 15;                // float4 slot in row
        const int r0 = tid >> 4;                // 0..15
        if (c4 < 15) {
            #pragma unroll
            for (int ch = 0; ch < C_; ++ch) {
                #pragma unroll
                for (int rg = 0; rg < 4; ++rg) {
                    const int r = r0 + rg * 16;
                    if (r < BOX) {              // only last group is partial
                        f32x4 v = (f32x4)(0.0f);
                        if (c4 < 14)
                            v = *reinterpret_cast<const f32x4*>(
                                img + ch * plane + (size_t)(by0 + r) * W_ + (bx0 + c4 * 4));
                        *reinterpret_cast<f32x4*>(
                            &smem[ch * CH_WORDS + r * LSTRIDE + c4 * 4]) = v;
                    }
                }
            }
        }
        // one zero guard row after ch2 (row-56 taps of ch0/ch1 land in the next
        // channel's finite row 0; ch2's land here; all are weight-0 taps).
        if (tid < 15)
            *reinterpret_cast<f32x4*>(&smem[C_ * CH_WORDS + tid * 4]) = (f32x4)(0.0f);
    }
    __syncthreads();

    // ---- per-thread: 4 consecutive output pixels in one row ----
    const int lr   = tid >> 3;                  // 0..31
    const int lc   = (tid & 7) * 4;             // 0,4,...,28
    const int row  = blockIdx.y * TILE + lr;
    const int col0 = blockIdx.x * TILE + lc;

    const float ysn = ((float)row  + 0.5f) * (2.0f / H_) - 1.0f;
    const float xsn = ((float)col0 + 0.5f) * (2.0f / W_) - 1.0f;
    // pixel-space sample coords; step exactly by (a, d) per output column.
    float ix = ((a * xsn + bb * ysn + tx + 1.0f) * W_ - 1.0f) * 0.5f;
    float iy = ((d * xsn + a  * ysn + ty + 1.0f) * H_ - 1.0f) * 0.5f;

    const int koff = by0 * LSTRIDE + bx0;
    float acc[C_][4];

    #pragma unroll
    for (int k = 0; k < 4; ++k) {
        const float rx  = reflect512(ix);
        const float ry  = reflect512(iy);
        const float x0f = floorf(rx);
        const float y0f = floorf(ry);
        const float fx  = rx - x0f;
        const float fy  = ry - y0f;
        const float ox  = 1.0f - fx;
        const float oy  = 1.0f - fy;
        const float w00 = ox * oy, w01 = fx * oy, w10 = ox * fy, w11 = fx * fy;

        // in-box by construction; +1 taps may hit zeroed pads only when w==0.
        const int idx = (int)y0f * LSTRIDE + (int)x0f - koff;
        const float* s = &smem[idx];
        #pragma unroll
        for (int ch = 0; ch < C_; ++ch) {
            const float* sc = s + ch * CH_WORDS;
            // pairs (0,1) and (60,61) merge into ds_read2_b32
            acc[ch][k] = sc[0] * w00 + sc[1] * w01
                       + sc[LSTRIDE] * w10 + sc[LSTRIDE + 1] * w11;
        }
        ix += a;
        iy += d;
    }

    float* o = out + (size_t)b * C_ * plane + (size_t)row * W_ + col0;
    #pragma unroll
    for (int ch = 0; ch < C_; ++ch) {
        const f32x4 v = {acc[ch][0], acc[ch][1], acc[ch][2], acc[ch][3]};
        __builtin_nontemporal_store(v, reinterpret_cast<f32x4*>(o + (size_t)ch * plane));
    }
}

extern "C" void kernel_launch(void* const* d_in, const int* in_sizes, int n_in,
                              void* d_out, int out_size, void* d_ws, size_t ws_size,
                              hipStream_t stream) {
    const float* x = (const float*)d_in[0];
    const float* p = (const float*)d_in[1];
    float* out = (float*)d_out;

    dim3 block(256, 1, 1);
    dim3 grid(W_ / TILE, H_ / TILE, B_);
    st_kernel<<<grid, block, 0, stream>>>(x, p, out);
}

// Round 3
// 186.070 us; speedup vs baseline: 1.1205x; 1.1205x over previous
//
#include <hip/hip_runtime.h>

// Spatial transformer: affine grid-sample, reflect padding, bilinear.
// x: (B=32, C=3, H=512, W=512) fp32; p: (B,4) fp32 = [tx, ty, theta, scale].
//
// R6: R5 showed ALL pipes <40% (VALU 23, HBM 26, occ 39) at the same 80us as
// R3 -> latency/concurrency bound + L2/L3 fabric traffic (staged reads are
// 308MB at L2, 3x the HBM view). Changes:
//  - channel-split: one block = one 32x32 tile of ONE channel. LDS 13.9KB ->
//    8 blocks/CU (wave-capped, 100% theoretical occupancy), 2.7x MLP.
//  - adaptive staging box: stage only ceil(2*ext) rows/cols (ext from actual
//    a,b) instead of worst-case 56x56. Avg ~30x36 -> ~3x less L2/L3 traffic.
//  - XCD-chunked work swizzle: consecutive work-ids (x/y-neighbor tiles of the
//    same plane) on the same XCD -> box overlap becomes L2 hits.
//  - zero-weight-tap safety with dynamic box: zero the float4 column at
//    c4==nw4 (when nw4<15) and a 64-word guard row at row nrows, so every
//    x0+1/y0+1 tap (weight exactly 0 when out of range) reads finite LDS.

#define B_ 32
#define C_ 3
#define H_ 512
#define W_ 512
#define TILE 32
#define LSTRIDE 60                    // up to 15 float4 per row
#define SMEM_WORDS (57 * LSTRIDE + 64)  // max 57 staged rows + 64-word guard

typedef float f32x4 __attribute__((ext_vector_type(4)));

// reflect onto [0, 511] with the reference's half-pixel convention.
// Exact for size=512: /1024, floor, and the mod subtraction are exact, so this
// is bit-identical to the reference's floor/fmod/parity form.
__device__ __forceinline__ float reflect512(float coord) {
    const float c = fabsf(coord + 0.5f);
    const float m = c - floorf(c * (1.0f / 1024.0f)) * 1024.0f;   // c mod 1024
    const float t = 512.0f - fabsf(m - 512.0f);
    return fminf(fmaxf(t - 0.5f, 0.0f), 511.0f);
}

__global__ __launch_bounds__(256, 8)
void st_kernel(const float* __restrict__ x, const float* __restrict__ p,
               float* __restrict__ out) {
    __shared__ float smem[SMEM_WORDS];          // 13,936 B -> 8 blocks/CU

    const int tid = threadIdx.x;

    // ---- XCD-chunked work swizzle (grid 24576 = 8 * 3072, bijective) ----
    const int bid = blockIdx.x;
    const int wid = (bid & 7) * 3072 + (bid >> 3);
    const int ch  = wid >> 13;                  // 0..2 (channel-major)
    const int rst = wid & 8191;
    const int b   = rst >> 8;                   // 0..31
    const int til = rst & 255;
    const int tlx = til & 15;
    const int tly = til >> 4;

    const float tx = p[b * 4 + 0];
    const float ty = p[b * 4 + 1];
    const float th = p[b * 4 + 2];
    const float ts = p[b * 4 + 3];
    const float cth = __cosf(th), sth = __sinf(th);   // th in [0,1): well-conditioned
    const float a  =  ts * cth;                 // ix step per output col
    const float bb = -ts * sth;                 // ix step per output row
    const float d  =  ts * sth;                 // iy step per output col (e == a)

    // ---- block-uniform adaptive staging box (center of the 32x32 tile) ----
    const float xs_c = ((float)(tlx * TILE) + 16.0f) * (2.0f / W_) - 1.0f;
    const float ys_c = ((float)(tly * TILE) + 16.0f) * (2.0f / H_) - 1.0f;
    const float gxc = a * xs_c + bb * ys_c + tx;
    const float gyc = d * xs_c + a  * ys_c + ty;
    const float rcx = reflect512(((gxc + 1.0f) * W_ - 1.0f) * 0.5f);
    const float rcy = reflect512(((gyc + 1.0f) * H_ - 1.0f) * 0.5f);
    // footprint half-extent 15.5*(|a|+|bb|); +3 slack covers floor/align.
    const float ext = 16.0f * (fabsf(a) + fabsf(bb)) + 3.0f;

    int bx0 = max((int)floorf(rcx - ext), 0) & ~3;          // 16B-aligned
    const int xhi = min((int)ceilf(rcx + ext) + 1, W_);     // +1: real x1 tap
    int nw4 = (xhi - bx0 + 3) >> 2;
    nw4 = min(min(nw4, 15), (W_ - bx0) >> 2);

    int by0 = max((int)floorf(rcy - ext), 0);
    const int yhi = min((int)ceilf(rcy + ext) + 1, H_);
    const int nrows = min(yhi - by0, 57);

    const size_t plane = (size_t)H_ * W_;
    const float* img = x + ((size_t)b * C_ + ch) * plane;

    // ---- stage nrows x (4*nw4) into LDS, coalesced float4 ----
    {
        const int c4 = tid & 15;                // float4 slot in row
        const float* gp = img + (size_t)by0 * W_ + bx0;
        for (int r = tid >> 4; r < nrows; r += 16) {
            float* ld = &smem[r * LSTRIDE];
            if (c4 < nw4) {
                const f32x4 v = *reinterpret_cast<const f32x4*>(gp + (size_t)r * W_ + c4 * 4);
                *reinterpret_cast<f32x4*>(ld + c4 * 4) = v;
            } else if (c4 == nw4 && nw4 < 15) {
                // zero column after staged width: weight-0 x1 taps read finite
                *reinterpret_cast<f32x4*>(ld + c4 * 4) = (f32x4)(0.0f);
            }
        }
        // 64-word zero guard row: weight-0 y1 taps (row == nrows) read finite
        if (tid < 16)
            *reinterpret_cast<f32x4*>(&smem[nrows * LSTRIDE + tid * 4]) = (f32x4)(0.0f);
    }
    __syncthreads();

    // ---- per-thread: 4 consecutive output pixels in one row ----
    const int lr   = tid >> 3;                  // 0..31
    const int lc   = (tid & 7) * 4;             // 0,4,...,28
    const int row  = tly * TILE + lr;
    const int col0 = tlx * TILE + lc;

    const float ysn = ((float)row  + 0.5f) * (2.0f / H_) - 1.0f;
    const float xsn = ((float)col0 + 0.5f) * (2.0f / W_) - 1.0f;
    float ix = ((a * xsn + bb * ysn + tx + 1.0f) * W_ - 1.0f) * 0.5f;
    float iy = ((d * xsn + a  * ysn + ty + 1.0f) * H_ - 1.0f) * 0.5f;

    const int koff = by0 * LSTRIDE + bx0;
    float acc[4];

    #pragma unroll
    for (int k = 0; k < 4; ++k) {
        const float rx  = reflect512(ix);
        const float ry  = reflect512(iy);
        const float x0f = floorf(rx);
        const float y0f = floorf(ry);
        const float fx  = rx - x0f;
        const float fy  = ry - y0f;
        const float ox  = 1.0f - fx;
        const float oy  = 1.0f - fy;
        const float w00 = ox * oy, w01 = fx * oy, w10 = ox * fy, w11 = fx * fy;

        const int idx = (int)y0f * LSTRIDE + (int)x0f - koff;
        const float* s = &smem[idx];
        // pairs (0,1) and (60,61) merge into ds_read2_b32
        acc[k] = s[0] * w00 + s[1] * w01
               + s[LSTRIDE] * w10 + s[LSTRIDE + 1] * w11;
        ix += a;
        iy += d;
    }

    float* o = out + ((size_t)b * C_ + ch) * plane + (size_t)row * W_ + col0;
    const f32x4 v = {acc[0], acc[1], acc[2], acc[3]};
    __builtin_nontemporal_store(v, reinterpret_cast<f32x4*>(o));
}

extern "C" void kernel_launch(void* const* d_in, const int* in_sizes, int n_in,
                              void* d_out, int out_size, void* d_ws, size_t ws_size,
                              hipStream_t stream) {
    const float* x = (const float*)d_in[0];
    const float* p = (const float*)d_in[1];
    float* out = (float*)d_out;

    dim3 block(256, 1, 1);
    dim3 grid((W_ / TILE) * (H_ / TILE) * B_ * C_, 1, 1);   // 24576
    st_kernel<<<grid, block, 0, stream>>>(x, p, out);
}